// Round 7
// baseline (464.033 us; speedup 1.0000x reference)
//
#include <hip/hip_runtime.h>
#include <math.h>
#include <limits.h>

// VQVAE: N=262144, K=1024, D=64. Outputs flat fp32: Z[N], q_with_st[N*64], 2 losses.
// R7: 3-kernel pipeline.
//  prep: csq (exact), cspre = 65536*csq + 5*2^24, codebook split scaled by -2^17,
//        transposed fp32 codebook cbT4 (for in-block rescore).
//  mega: phase1 MFMA distances; acc directly holds quantized score with constant
//        exponent -> key = (bits(acc)<<10) + code, u32 argmin/top-2 (5 VALU/score).
//        phase2: block-local exact rescore of ambiguous rows (gap <= T), bitwise
//        reference-matching fp32 formula (verified absmax 0.0 rounds 1/3/4/5/6).
//        phase3: fused epilogue (gather, q_with_st, loss partial per block).
//  finalize: loss reduction.

static constexpr int NROWS = 262144;
static constexpr int KC    = 1024;
static constexpr int DIM   = 64;

// d_ws layout (bytes) — max end 540672 < 561160 proven-safe from prior rounds
static constexpr size_t CSQ_OFF    = 0;          // 1024 f32
static constexpr size_t CSPRE_OFF  = 4096;       // 1024 f32 (= 65536*csq + 5*2^24)
static constexpr size_t CSPLIT_OFF = 8192;       // 16 chk x 16 slot x 64 code x 16B = 256 KB
static constexpr size_t PART_OFF   = 270336;     // 1024 doubles (8 KB)
static constexpr size_t CBT_OFF    = 278528;     // 16384 float4 (256 KB) -> ends 540672

static constexpr float BIGC = 83886080.0f;       // 5 * 2^24

typedef __attribute__((ext_vector_type(8)))  short   short8;
typedef __attribute__((ext_vector_type(8)))  unsigned short ushort8;
typedef __attribute__((ext_vector_type(16))) float   f32x16;

static __device__ __forceinline__ unsigned short bf16rn(float f) {
    unsigned u = __float_as_uint(f);
    u += 0x7fffu + ((u >> 16) & 1u);      // round-nearest-even to bf16
    return (unsigned short)(u >> 16);
}
static __device__ __forceinline__ unsigned umin(unsigned a, unsigned b) { return a < b ? a : b; }
static __device__ __forceinline__ unsigned umax(unsigned a, unsigned b) { return a > b ? a : b; }

// ------------------------------------------------ prep
// csplit ushort index = chk*8192 + slot*512 + c_l*8 + e ; chk=c>>6, c_l=c&63
// slot for hi of dim d: d>>3 ; lo: 8+(d>>3) ; e = d&7. Values scaled by -2^17.
// cbT4[q*1024 + c] = cb[c][4q..4q+3] (fp32, for coalesced rescore reads).
__global__ __launch_bounds__(64) void prep_kernel(const float* __restrict__ cb,
                                                  float* __restrict__ csq,
                                                  float* __restrict__ cspre,
                                                  unsigned short* __restrict__ cs,
                                                  float4* __restrict__ cbt4) {
#pragma clang fp contract(off)
    const int c = blockIdx.x * 64 + threadIdx.x;
    const float4* row = reinterpret_cast<const float4*>(cb + (size_t)c * DIM);
    float e[64];
#pragma unroll
    for (int q = 0; q < 16; ++q) {
        float4 v = row[q];
        cbt4[q * 1024 + c] = v;                         // transposed copy
        e[q * 4 + 0] = v.x; e[q * 4 + 1] = v.y;
        e[q * 4 + 2] = v.z; e[q * 4 + 3] = v.w;
    }
    float r[8];
#pragma unroll
    for (int g = 0; g < 8; ++g)
#pragma unroll
        for (int j = 0; j < 8; ++j) {
            float sq = e[8 * g + j] * e[8 * g + j];     // rounded square (no fma)
            if (g == 0) r[j] = sq; else r[j] += sq;
        }
    float s = ((r[0] + r[1]) + (r[2] + r[3])) + ((r[4] + r[5]) + (r[6] + r[7]));
    csq[c]   = s;
    cspre[c] = 65536.0f * s + BIGC;                     // one rounding (ulp 8 quanta)

    const int chk = c >> 6, c_l = c & 63;
    unsigned short* base = cs + (size_t)chk * 8192 + (size_t)c_l * 8;
#pragma unroll
    for (int g = 0; g < 8; ++g) {
        ushort8 hi, lo;
#pragma unroll
        for (int j = 0; j < 8; ++j) {
            float f = e[8 * g + j] * -131072.0f;        // exact pow2 scale
            unsigned short hb = bf16rn(f);
            float fh = __uint_as_float((unsigned)hb << 16);
            hi[j] = hb;
            lo[j] = bf16rn(f - fh);
        }
        *reinterpret_cast<ushort8*>(base + g * 512)       = hi;
        *reinterpret_cast<ushort8*>(base + (8 + g) * 512) = lo;
    }
}

// ------------------------------------------------ mega: MFMA argmin + rescore + epilogue
#define STAGE(buf_, chk_) do {                                                          \
    const char* _s = (const char*)csplit + (size_t)(chk_) * 16384                       \
                     + (size_t)(w * 4) * 1024 + (size_t)lane * 16;                      \
    char* _d = (char*)(&bbuf[buf_][0]) + (size_t)(w * 4) * 1024;                        \
    _Pragma("unroll")                                                                   \
    for (int _it = 0; _it < 4; ++_it)                                                   \
        __builtin_amdgcn_global_load_lds(                                               \
            (const __attribute__((address_space(1))) unsigned int*)(_s + _it * 1024),   \
            (__attribute__((address_space(3))) unsigned int*)(_d + _it * 1024),         \
            16, 0, 0);                                                                  \
} while (0)

__global__ __launch_bounds__(256, 3) void vq_mega_kernel(
        const float* __restrict__ x, const float* __restrict__ cb,
        const unsigned short* __restrict__ csplit,
        const float* __restrict__ cspre_g, const float4* __restrict__ cbt4,
        const float* __restrict__ csq, float* __restrict__ zout,
        float* __restrict__ qout, double* __restrict__ partial) {
#pragma clang fp contract(off)
    __shared__ unsigned short bbuf[2][8192];   // 32 KB
    __shared__ float cspre_s[1024];            // 4 KB
    __shared__ float xs[4][64];                // 1 KB
    __shared__ int   zloc[256];                // 1 KB
    __shared__ int   llist[256];               // 1 KB
    __shared__ int   lcnt;
    __shared__ double wsum[4];

    const int tid  = threadIdx.x;
    const int w    = tid >> 6;
    const int lane = tid & 63;
    const int h    = lane >> 5;
    const int cl5  = lane & 31;
    const int rowbase0 = blockIdx.x * 256;
    const int rowbase  = rowbase0 + w * 64;

    if (tid == 0) lcnt = 0;
    STAGE(0, 0);
    {   // cspre -> LDS
        float4 v = reinterpret_cast<const float4*>(cspre_g)[tid];
        reinterpret_cast<float4*>(cspre_s)[tid] = v;
    }

    // ---- phase 1 prologue: x fragments (B-operand), bf16 hi/lo split in regs
    short8 xh[2][4], xl[2][4];
    float sa[2];
#pragma unroll
    for (int R = 0; R < 2; ++R) {
        const float* xrow = x + (size_t)(rowbase + R * 32 + cl5) * DIM;
        float s = 0.0f;
#pragma unroll
        for (int j = 0; j < 4; ++j) {
            float4 p0 = *reinterpret_cast<const float4*>(xrow + j * 16 + h * 8);
            float4 p1 = *reinterpret_cast<const float4*>(xrow + j * 16 + h * 8 + 4);
            float v[8] = {p0.x, p0.y, p0.z, p0.w, p1.x, p1.y, p1.z, p1.w};
#pragma unroll
            for (int e = 0; e < 8; ++e) {
                float f = v[e];
                s += fabsf(f);
                unsigned short hb = bf16rn(f);
                float fh = __uint_as_float((unsigned)hb << 16);
                xh[R][j][e] = (short)hb;
                xl[R][j][e] = (short)bf16rn(f - fh);
            }
        }
        s += __shfl_xor(s, 32, 64);            // complementary d-half, same row
        sa[R] = s;
    }
    __syncthreads();                           // chunk0 + cspre + lcnt ready

    unsigned k1[2] = {0xFFFFFFFFu, 0xFFFFFFFFu};
    unsigned k2[2] = {0xFFFFFFFFu, 0xFFFFFFFFu};
    const int lofs = cl5 * 16 + h * 1024;      // per-thread A-read byte offset
    static constexpr int IDX[16] = {0,1,2,3, 8,9,10,11, 16,17,18,19, 24,25,26,27};

    for (int chk = 0; chk < 16; ++chk) {
        const int cur = chk & 1;
        if (chk < 15) STAGE(cur ^ 1, chk + 1);
        const char* bb = (const char*)(&bbuf[cur][0]);
#pragma unroll
        for (int t = 0; t < 2; ++t) {
            const unsigned cbase = (unsigned)(chk * 64 + t * 32 + 4 * h);
            const float* cp = &cspre_s[chk * 64 + t * 32 + 4 * h];
            float4 g0 = *reinterpret_cast<const float4*>(cp);
            float4 g1 = *reinterpret_cast<const float4*>(cp + 8);
            float4 g2 = *reinterpret_cast<const float4*>(cp + 16);
            float4 g3 = *reinterpret_cast<const float4*>(cp + 24);
            f32x16 ini;
            ini[0]  = g0.x; ini[1]  = g0.y; ini[2]  = g0.z; ini[3]  = g0.w;
            ini[4]  = g1.x; ini[5]  = g1.y; ini[6]  = g1.z; ini[7]  = g1.w;
            ini[8]  = g2.x; ini[9]  = g2.y; ini[10] = g2.z; ini[11] = g2.w;
            ini[12] = g3.x; ini[13] = g3.y; ini[14] = g3.z; ini[15] = g3.w;

            const char* bp = bb + t * 512 + lofs;
            f32x16 a0, a1;
            {   // j = 0: ini is shared C for both accs (read-only C operand)
                short8 bch = *reinterpret_cast<const short8*>(bp);
                short8 bcl = *reinterpret_cast<const short8*>(bp + 8192);
                a0 = __builtin_amdgcn_mfma_f32_32x32x16_bf16(bch, xh[0][0], ini, 0, 0, 0);
                a1 = __builtin_amdgcn_mfma_f32_32x32x16_bf16(bch, xh[1][0], ini, 0, 0, 0);
                a0 = __builtin_amdgcn_mfma_f32_32x32x16_bf16(bch, xl[0][0], a0, 0, 0, 0);
                a1 = __builtin_amdgcn_mfma_f32_32x32x16_bf16(bch, xl[1][0], a1, 0, 0, 0);
                a0 = __builtin_amdgcn_mfma_f32_32x32x16_bf16(bcl, xh[0][0], a0, 0, 0, 0);
                a1 = __builtin_amdgcn_mfma_f32_32x32x16_bf16(bcl, xh[1][0], a1, 0, 0, 0);
            }
#pragma unroll
            for (int j = 1; j < 4; ++j) {
                short8 bch = *reinterpret_cast<const short8*>(bp + j * 2048);
                short8 bcl = *reinterpret_cast<const short8*>(bp + 8192 + j * 2048);
                a0 = __builtin_amdgcn_mfma_f32_32x32x16_bf16(bch, xh[0][j], a0, 0, 0, 0);
                a1 = __builtin_amdgcn_mfma_f32_32x32x16_bf16(bch, xh[1][j], a1, 0, 0, 0);
                a0 = __builtin_amdgcn_mfma_f32_32x32x16_bf16(bch, xl[0][j], a0, 0, 0, 0);
                a1 = __builtin_amdgcn_mfma_f32_32x32x16_bf16(bch, xl[1][j], a1, 0, 0, 0);
                a0 = __builtin_amdgcn_mfma_f32_32x32x16_bf16(bcl, xh[0][j], a0, 0, 0, 0);
                a1 = __builtin_amdgcn_mfma_f32_32x32x16_bf16(bcl, xh[1][j], a1, 0, 0, 0);
            }
            // acc = BIGC + 65536*(csq - 2*dot): constant exponent (2^26 bucket),
            // mantissa bit22 == 0 -> key = (bits<<10)+code is u32-monotone.
#pragma unroll
            for (int p = 0; p < 8; ++p) {
                const int r = 2 * p, r2 = 2 * p + 1;
                {
                    unsigned ka = (__float_as_uint(a0[r])  << 10) + cbase + IDX[r];
                    unsigned kb = (__float_as_uint(a0[r2]) << 10) + cbase + IDX[r2];
                    unsigned pmin = umin(ka, kb), pmax = umax(ka, kb);
                    unsigned tt = umax(pmin, k1[0]);
                    k2[0] = umin(k2[0], umin(tt, pmax));
                    k1[0] = umin(k1[0], pmin);
                }
                {
                    unsigned ka = (__float_as_uint(a1[r])  << 10) + cbase + IDX[r];
                    unsigned kb = (__float_as_uint(a1[r2]) << 10) + cbase + IDX[r2];
                    unsigned pmin = umin(ka, kb), pmax = umax(ka, kb);
                    unsigned tt = umax(pmin, k1[1]);
                    k2[1] = umin(k2[1], umin(tt, pmax));
                    k1[1] = umin(k1[1], pmin);
                }
            }
        }
        __syncthreads();           // my reads done; staged chunk landed (vmcnt drain)
    }

    // merge complementary code-subsets (lane <-> lane^32); keys embed idx so
    // u32 min is lex (quantized score, idx) min.
    unsigned K1[2], K2[2];
#pragma unroll
    for (int R = 0; R < 2; ++R) {
        unsigned o1 = (unsigned)__shfl_xor((int)k1[R], 32, 64);
        unsigned o2 = (unsigned)__shfl_xor((int)k2[R], 32, 64);
        unsigned mn = umin(k1[R], o1), mx = umax(k1[R], o1);
        K1[R] = mn;
        K2[R] = umin(umin(k2[R], o2), mx);
    }
    {
        const unsigned bk1 = h ? K1[1] : K1[0];
        const unsigned bk2 = h ? K2[1] : K2[0];
        const float    SA  = h ? sa[1] : sa[0];
        const int rl  = w * 64 + h * 32 + cl5;
        const int row = rowbase0 + rl;
        const int code = (int)(bk1 & 1023u);
        zout[row] = (float)code;
        zloc[rl]  = code;
        // key quantum = 8*2^-16 = 1.2207e-4 dist; T = 1.2e-4*SA + 0.012
        unsigned Tq = (unsigned)(8192.0f * (1.2e-4f * SA + 0.012f)) + 2u;
        if ((bk2 - bk1) < (Tq << 10)) {
            int id = atomicAdd(&lcnt, 1);
            llist[id] = rl;
        }
    }
    __syncthreads();                           // list complete

    // ---- phase 2: exact in-block rescore (bitwise reference-matching, R6 body)
    {
        const int cnt = lcnt;
        for (int i = w; i < cnt; i += 4) {
            const int rl2  = llist[i];
            const int row2 = rowbase0 + rl2;
            if (lane < 16) {
                float4 v = reinterpret_cast<const float4*>(x + (size_t)row2 * DIM)[lane];
                *reinterpret_cast<float4*>(&xs[w][lane * 4]) = v;
            }
            __builtin_amdgcn_wave_barrier();

            float r8[8];
#pragma unroll
            for (int g = 0; g < 8; ++g)
#pragma unroll
                for (int j = 0; j < 8; ++j) {
                    float xv = xs[w][8 * g + j];
                    float sq = xv * xv;
                    if (g == 0) r8[j] = sq; else r8[j] += sq;
                }
            float xsq = ((r8[0] + r8[1]) + (r8[2] + r8[3])) + ((r8[4] + r8[5]) + (r8[6] + r8[7]));

            float bm = INFINITY; int bi = 0;
#pragma unroll 2
            for (int cc = 0; cc < 16; ++cc) {
                int c = cc * 64 + lane;               // in-lane ascending
                float dot = 0.0f;
#pragma unroll
                for (int q = 0; q < 16; ++q) {
                    float4 v  = cbt4[q * 1024 + c];   // coalesced
                    float4 xv = *reinterpret_cast<const float4*>(&xs[w][q * 4]);
                    dot = __builtin_fmaf(v.x, xv.x, dot);
                    dot = __builtin_fmaf(v.y, xv.y, dot);
                    dot = __builtin_fmaf(v.z, xv.z, dot);
                    dot = __builtin_fmaf(v.w, xv.w, dot);
                }
                float dist = (xsq - 2.0f * dot) + csq[c];
                if (dist < bm) { bm = dist; bi = c; }
            }
#pragma unroll
            for (int m = 1; m <= 32; m <<= 1) {
                float ov = __shfl_xor(bm, m, 64);
                int   oi = __shfl_xor(bi, m, 64);
                if (ov < bm || (ov == bm && oi < bi)) { bm = ov; bi = oi; }
            }
            if (lane == 0) { zout[row2] = (float)bi; zloc[rl2] = bi; }
            __builtin_amdgcn_wave_barrier();
        }
    }
    __syncthreads();                           // zloc final

    // ---- phase 3: fused epilogue (gather + q_with_st + loss partial)
    double lsum = 0.0;
#pragma unroll
    for (int rr = 0; rr < 4; ++rr) {
        const int rl3  = rr * 64 + (tid >> 2);
        const int row3 = rowbase0 + rl3;
        const int d0   = (tid & 3) * 16;
        const float4* xr = reinterpret_cast<const float4*>(x + (size_t)row3 * DIM + d0);
        const int z = zloc[rl3];
        const float4* qr = reinterpret_cast<const float4*>(cb + (size_t)z * DIM + d0);
        float4* op = reinterpret_cast<float4*>(qout + (size_t)row3 * DIM + d0);
#pragma unroll
        for (int q = 0; q < 4; ++q) {
            float4 xv = xr[q];
            float4 qv = qr[q];
            float da = qv.x - xv.x, db = qv.y - xv.y, dc = qv.z - xv.z, dd = qv.w - xv.w;
            float4 o;
            o.x = xv.x + da; o.y = xv.y + db; o.z = xv.z + dc; o.w = xv.w + dd;
            op[q] = o;
            lsum += (double)(da * da) + (double)(db * db)
                  + (double)(dc * dc) + (double)(dd * dd);
        }
    }
#pragma unroll
    for (int s = 32; s >= 1; s >>= 1) lsum += __shfl_down(lsum, s, 64);
    if (lane == 0) wsum[w] = lsum;
    __syncthreads();
    if (tid == 0)
        partial[blockIdx.x] = (wsum[0] + wsum[1]) + (wsum[2] + wsum[3]);
}

// ---------------------------------------------------------------- finalize
__global__ void finalize_kernel(const double* __restrict__ partial,
                                float* __restrict__ losses) {
    double s = 0.0;
    int lane = threadIdx.x;
    for (int i = lane; i < 1024; i += 64) s += partial[i];
#pragma unroll
    for (int sh = 32; sh >= 1; sh >>= 1) s += __shfl_down(s, sh, 64);
    if (lane == 0) {
        float v = (float)(s / 16777216.0);
        losses[0] = v;
        losses[1] = v;
    }
}

extern "C" void kernel_launch(void* const* d_in, const int* in_sizes, int n_in,
                              void* d_out, int out_size, void* d_ws, size_t ws_size,
                              hipStream_t stream) {
    const float* x  = (const float*)d_in[0];
    const float* cb = (const float*)d_in[1];
    float* out    = (float*)d_out;
    float* zout   = out;
    float* qout   = out + NROWS;
    float* losses = out + NROWS + (size_t)NROWS * DIM;

    float*          csq     = (float*)((char*)d_ws + CSQ_OFF);
    float*          cspre   = (float*)((char*)d_ws + CSPRE_OFF);
    unsigned short* csplit  = (unsigned short*)((char*)d_ws + CSPLIT_OFF);
    double*         partial = (double*)((char*)d_ws + PART_OFF);
    float4*         cbt4    = (float4*)((char*)d_ws + CBT_OFF);

    prep_kernel<<<16, 64, 0, stream>>>(cb, csq, cspre, csplit, cbt4);
    vq_mega_kernel<<<NROWS / 256, 256, 0, stream>>>(x, cb, csplit, cspre, cbt4,
                                                    csq, zout, qout, partial);
    finalize_kernel<<<1, 64, 0, stream>>>(partial, losses);
}

// Round 8
// 318.849 us; speedup vs baseline: 1.4553x; 1.4553x over previous
//
#include <hip/hip_runtime.h>
#include <math.h>
#include <limits.h>

// VQVAE: N=262144, K=1024, D=64. Outputs flat fp32: Z[N], q_with_st[N*64], 2 losses.
// R8 structure: prep -> mega(phase1 MFMA argmin + phase2 in-block exact rescore)
//               -> epilogue (standalone 4096-block streaming, R6-proven) -> finalize.
// Key scheme: acc init = 65536*csq (EXACT pow2 scale); codebook split scaled by
// -2^17 so acc = 65536*(csq - 2*dot); key = (bits(acc + 5*2^24) << 10) + code is
// u32-monotone (constant exponent bucket, mantissa bit22=0). Ambiguous rows
// (top-2 key gap <= Tq) rescored with the bitwise reference-matching fp32
// formula (verified absmax 0.0 in rounds 1/3/4/5/6/7).

static constexpr int NROWS = 262144;
static constexpr int KC    = 1024;
static constexpr int DIM   = 64;

// d_ws layout (bytes); proven ws >= 565256 from rounds 4-6.
static constexpr size_t CSQ_OFF    = 0;          // 1024 f32
static constexpr size_t CSPRE_OFF  = 4096;       // 1024 f32 (= 65536*csq, exact)
static constexpr size_t CSPLIT_OFF = 8192;       // 256 KB -> ends 270336
static constexpr size_t PART_OFF   = 270336;     // 4096 doubles -> ends 303104

static constexpr float BIGC = 83886080.0f;       // 5 * 2^24

typedef __attribute__((ext_vector_type(8)))  short   short8;
typedef __attribute__((ext_vector_type(8)))  unsigned short ushort8;
typedef __attribute__((ext_vector_type(16))) float   f32x16;

static __device__ __forceinline__ unsigned short bf16rn(float f) {
    unsigned u = __float_as_uint(f);
    u += 0x7fffu + ((u >> 16) & 1u);      // round-nearest-even to bf16
    return (unsigned short)(u >> 16);
}
static __device__ __forceinline__ unsigned umin(unsigned a, unsigned b) { return a < b ? a : b; }
static __device__ __forceinline__ unsigned umax(unsigned a, unsigned b) { return a > b ? a : b; }

// ------------------------------------------------ prep
// csplit ushort index = chk*8192 + slot*512 + c_l*8 + e ; chk=c>>6, c_l=c&63
// slot for hi of dim d: d>>3 ; lo: 8+(d>>3) ; e = d&7. Values scaled by -2^17.
// cbT4[q*1024 + c] = cb[c][4q..4q+3] (fp32) -> lives in qout region until epilogue.
__global__ __launch_bounds__(64) void prep_kernel(const float* __restrict__ cb,
                                                  float* __restrict__ csq,
                                                  float* __restrict__ cspre,
                                                  unsigned short* __restrict__ cs,
                                                  float4* __restrict__ cbt4) {
#pragma clang fp contract(off)
    const int c = blockIdx.x * 64 + threadIdx.x;
    const float4* row = reinterpret_cast<const float4*>(cb + (size_t)c * DIM);
    float e[64];
#pragma unroll
    for (int q = 0; q < 16; ++q) {
        float4 v = row[q];
        cbt4[q * 1024 + c] = v;                         // transposed copy
        e[q * 4 + 0] = v.x; e[q * 4 + 1] = v.y;
        e[q * 4 + 2] = v.z; e[q * 4 + 3] = v.w;
    }
    float r[8];
#pragma unroll
    for (int g = 0; g < 8; ++g)
#pragma unroll
        for (int j = 0; j < 8; ++j) {
            float sq = e[8 * g + j] * e[8 * g + j];     // rounded square (no fma)
            if (g == 0) r[j] = sq; else r[j] += sq;
        }
    float s = ((r[0] + r[1]) + (r[2] + r[3])) + ((r[4] + r[5]) + (r[6] + r[7]));
    csq[c]   = s;
    cspre[c] = 65536.0f * s;                            // EXACT (pow2 scale)

    const int chk = c >> 6, c_l = c & 63;
    unsigned short* base = cs + (size_t)chk * 8192 + (size_t)c_l * 8;
#pragma unroll
    for (int g = 0; g < 8; ++g) {
        ushort8 hi, lo;
#pragma unroll
        for (int j = 0; j < 8; ++j) {
            float f = e[8 * g + j] * -131072.0f;        // exact pow2 scale
            unsigned short hb = bf16rn(f);
            float fh = __uint_as_float((unsigned)hb << 16);
            hi[j] = hb;
            lo[j] = bf16rn(f - fh);
        }
        *reinterpret_cast<ushort8*>(base + g * 512)       = hi;
        *reinterpret_cast<ushort8*>(base + (8 + g) * 512) = lo;
    }
}

// ------------------------------------------------ mega: MFMA argmin + in-block rescore
#define STAGE(buf_, chk_) do {                                                          \
    const char* _s = (const char*)csplit + (size_t)(chk_) * 16384                       \
                     + (size_t)(w * 4) * 1024 + (size_t)lane * 16;                      \
    char* _d = (char*)(&bbuf[buf_][0]) + (size_t)(w * 4) * 1024;                        \
    _Pragma("unroll")                                                                   \
    for (int _it = 0; _it < 4; ++_it)                                                   \
        __builtin_amdgcn_global_load_lds(                                               \
            (const __attribute__((address_space(1))) unsigned int*)(_s + _it * 1024),   \
            (__attribute__((address_space(3))) unsigned int*)(_d + _it * 1024),         \
            16, 0, 0);                                                                  \
} while (0)

__global__ __launch_bounds__(256, 3) void vq_mega_kernel(
        const float* __restrict__ x, const unsigned short* __restrict__ csplit,
        const float* __restrict__ cspre_g, const float4* __restrict__ cbt4,
        const float* __restrict__ csq, float* __restrict__ zout) {
#pragma clang fp contract(off)
    __shared__ unsigned short bbuf[2][8192];   // 32 KB
    __shared__ float cspre_s[1024];            // 4 KB
    __shared__ float xs[4][64];                // 1 KB
    __shared__ int   llist[256];               // 1 KB
    __shared__ int   lcnt;

    const int tid  = threadIdx.x;
    const int w    = tid >> 6;
    const int lane = tid & 63;
    const int h    = lane >> 5;
    const int cl5  = lane & 31;
    const int rowbase0 = blockIdx.x * 256;
    const int rowbase  = rowbase0 + w * 64;

    if (tid == 0) lcnt = 0;
    STAGE(0, 0);
    {   // cspre -> LDS
        float4 v = reinterpret_cast<const float4*>(cspre_g)[tid];
        reinterpret_cast<float4*>(cspre_s)[tid] = v;
    }

    // ---- phase 1 prologue: x fragments (B-operand), bf16 hi/lo split in regs
    short8 xh[2][4], xl[2][4];
    float sa[2];
#pragma unroll
    for (int R = 0; R < 2; ++R) {
        const float* xrow = x + (size_t)(rowbase + R * 32 + cl5) * DIM;
        float s = 0.0f;
#pragma unroll
        for (int j = 0; j < 4; ++j) {
            float4 p0 = *reinterpret_cast<const float4*>(xrow + j * 16 + h * 8);
            float4 p1 = *reinterpret_cast<const float4*>(xrow + j * 16 + h * 8 + 4);
            float v[8] = {p0.x, p0.y, p0.z, p0.w, p1.x, p1.y, p1.z, p1.w};
#pragma unroll
            for (int e = 0; e < 8; ++e) {
                float f = v[e];
                s += fabsf(f);
                unsigned short hb = bf16rn(f);
                float fh = __uint_as_float((unsigned)hb << 16);
                xh[R][j][e] = (short)hb;
                xl[R][j][e] = (short)bf16rn(f - fh);
            }
        }
        s += __shfl_xor(s, 32, 64);            // complementary d-half, same row
        sa[R] = s;
    }
    __syncthreads();                           // chunk0 + cspre + lcnt ready

    unsigned k1[2] = {0xFFFFFFFFu, 0xFFFFFFFFu};
    unsigned k2[2] = {0xFFFFFFFFu, 0xFFFFFFFFu};
    const int lofs = cl5 * 16 + h * 1024;      // per-thread A-read byte offset
    static constexpr int IDX[16] = {0,1,2,3, 8,9,10,11, 16,17,18,19, 24,25,26,27};

    for (int chk = 0; chk < 16; ++chk) {
        const int cur = chk & 1;
        if (chk < 15) STAGE(cur ^ 1, chk + 1);
        const char* bb = (const char*)(&bbuf[cur][0]);
#pragma unroll
        for (int t = 0; t < 2; ++t) {
            const unsigned cbase = (unsigned)(chk * 64 + t * 32 + 4 * h);
            const float* cp = &cspre_s[chk * 64 + t * 32 + 4 * h];
            float4 g0 = *reinterpret_cast<const float4*>(cp);
            float4 g1 = *reinterpret_cast<const float4*>(cp + 8);
            float4 g2 = *reinterpret_cast<const float4*>(cp + 16);
            float4 g3 = *reinterpret_cast<const float4*>(cp + 24);
            f32x16 ini;
            ini[0]  = g0.x; ini[1]  = g0.y; ini[2]  = g0.z; ini[3]  = g0.w;
            ini[4]  = g1.x; ini[5]  = g1.y; ini[6]  = g1.z; ini[7]  = g1.w;
            ini[8]  = g2.x; ini[9]  = g2.y; ini[10] = g2.z; ini[11] = g2.w;
            ini[12] = g3.x; ini[13] = g3.y; ini[14] = g3.z; ini[15] = g3.w;

            const char* bp = bb + t * 512 + lofs;
            f32x16 a0, a1;
            {   // j = 0: ini is shared read-only C for both acc chains
                short8 bch = *reinterpret_cast<const short8*>(bp);
                short8 bcl = *reinterpret_cast<const short8*>(bp + 8192);
                a0 = __builtin_amdgcn_mfma_f32_32x32x16_bf16(bch, xh[0][0], ini, 0, 0, 0);
                a1 = __builtin_amdgcn_mfma_f32_32x32x16_bf16(bch, xh[1][0], ini, 0, 0, 0);
                a0 = __builtin_amdgcn_mfma_f32_32x32x16_bf16(bch, xl[0][0], a0, 0, 0, 0);
                a1 = __builtin_amdgcn_mfma_f32_32x32x16_bf16(bch, xl[1][0], a1, 0, 0, 0);
                a0 = __builtin_amdgcn_mfma_f32_32x32x16_bf16(bcl, xh[0][0], a0, 0, 0, 0);
                a1 = __builtin_amdgcn_mfma_f32_32x32x16_bf16(bcl, xh[1][0], a1, 0, 0, 0);
            }
#pragma unroll
            for (int j = 1; j < 4; ++j) {
                short8 bch = *reinterpret_cast<const short8*>(bp + j * 2048);
                short8 bcl = *reinterpret_cast<const short8*>(bp + 8192 + j * 2048);
                a0 = __builtin_amdgcn_mfma_f32_32x32x16_bf16(bch, xh[0][j], a0, 0, 0, 0);
                a1 = __builtin_amdgcn_mfma_f32_32x32x16_bf16(bch, xh[1][j], a1, 0, 0, 0);
                a0 = __builtin_amdgcn_mfma_f32_32x32x16_bf16(bch, xl[0][j], a0, 0, 0, 0);
                a1 = __builtin_amdgcn_mfma_f32_32x32x16_bf16(bch, xl[1][j], a1, 0, 0, 0);
                a0 = __builtin_amdgcn_mfma_f32_32x32x16_bf16(bcl, xh[0][j], a0, 0, 0, 0);
                a1 = __builtin_amdgcn_mfma_f32_32x32x16_bf16(bcl, xh[1][j], a1, 0, 0, 0);
            }
            // acc = 65536*(csq - 2*dot); z = acc + BIGC (one rounding, <= 0.5 ulp);
            // key = (bits(z)<<10) + code : u32-monotone (const exponent, bit22=0).
#pragma unroll
            for (int p = 0; p < 8; ++p) {
                const int r = 2 * p, r2 = 2 * p + 1;
                {
                    unsigned ka = (__float_as_uint(a0[r]  + BIGC) << 10) + cbase + IDX[r];
                    unsigned kb = (__float_as_uint(a0[r2] + BIGC) << 10) + cbase + IDX[r2];
                    unsigned pmin = umin(ka, kb), pmax = umax(ka, kb);
                    unsigned tt = umax(pmin, k1[0]);
                    k2[0] = umin(k2[0], umin(tt, pmax));
                    k1[0] = umin(k1[0], pmin);
                }
                {
                    unsigned ka = (__float_as_uint(a1[r]  + BIGC) << 10) + cbase + IDX[r];
                    unsigned kb = (__float_as_uint(a1[r2] + BIGC) << 10) + cbase + IDX[r2];
                    unsigned pmin = umin(ka, kb), pmax = umax(ka, kb);
                    unsigned tt = umax(pmin, k1[1]);
                    k2[1] = umin(k2[1], umin(tt, pmax));
                    k1[1] = umin(k1[1], pmin);
                }
            }
        }
        __syncthreads();           // my reads done; staged chunk landed (vmcnt drain)
    }

    // merge complementary code-subsets (lane <-> lane^32); keys embed idx so
    // u32 min is lex (quantized score, idx) min.
    unsigned K1[2], K2[2];
#pragma unroll
    for (int R = 0; R < 2; ++R) {
        unsigned o1 = (unsigned)__shfl_xor((int)k1[R], 32, 64);
        unsigned o2 = (unsigned)__shfl_xor((int)k2[R], 32, 64);
        unsigned mn = umin(k1[R], o1), mx = umax(k1[R], o1);
        K1[R] = mn;
        K2[R] = umin(umin(k2[R], o2), mx);
    }
    {
        const unsigned bk1 = h ? K1[1] : K1[0];
        const unsigned bk2 = h ? K2[1] : K2[0];
        const float    SA  = h ? sa[1] : sa[0];
        const int rl  = w * 64 + h * 32 + cl5;
        zout[rowbase0 + rl] = (float)(bk1 & 1023u);
        // key-bit quantum = 1.22e-4 dist (8192 = 1/1.22e-4).
        unsigned Tq = (unsigned)(8192.0f * (1.2e-4f * SA + 8e-4f)) + 2u;
        if ((bk2 - bk1) < (Tq << 10)) {
            int id = atomicAdd(&lcnt, 1);
            if (id < 256) llist[id] = rl;
        }
    }
    __syncthreads();                           // list complete

    // ---- phase 2: exact in-block rescore (bitwise reference-matching, R6 body)
    {
        int cnt = lcnt; if (cnt > 256) cnt = 256;
        for (int i = w; i < cnt; i += 4) {
            const int row2 = rowbase0 + llist[i];
            if (lane < 16) {
                float4 v = reinterpret_cast<const float4*>(x + (size_t)row2 * DIM)[lane];
                *reinterpret_cast<float4*>(&xs[w][lane * 4]) = v;
            }
            __builtin_amdgcn_wave_barrier();

            float r8[8];
#pragma unroll
            for (int g = 0; g < 8; ++g)
#pragma unroll
                for (int j = 0; j < 8; ++j) {
                    float xv = xs[w][8 * g + j];
                    float sq = xv * xv;
                    if (g == 0) r8[j] = sq; else r8[j] += sq;
                }
            float xsq = ((r8[0] + r8[1]) + (r8[2] + r8[3])) + ((r8[4] + r8[5]) + (r8[6] + r8[7]));

            float bm = INFINITY; int bi = 0;
#pragma unroll 2
            for (int cc = 0; cc < 16; ++cc) {
                int c = cc * 64 + lane;               // in-lane ascending
                float dot = 0.0f;
#pragma unroll
                for (int q = 0; q < 16; ++q) {
                    float4 v  = cbt4[q * 1024 + c];   // coalesced
                    float4 xv = *reinterpret_cast<const float4*>(&xs[w][q * 4]);
                    dot = __builtin_fmaf(v.x, xv.x, dot);
                    dot = __builtin_fmaf(v.y, xv.y, dot);
                    dot = __builtin_fmaf(v.z, xv.z, dot);
                    dot = __builtin_fmaf(v.w, xv.w, dot);
                }
                float dist = (xsq - 2.0f * dot) + csq[c];
                if (dist < bm) { bm = dist; bi = c; }
            }
#pragma unroll
            for (int m = 1; m <= 32; m <<= 1) {
                float ov = __shfl_xor(bm, m, 64);
                int   oi = __shfl_xor(bi, m, 64);
                if (ov < bm || (ov == bm && oi < bi)) { bm = ov; bi = oi; }
            }
            if (lane == 0) zout[row2] = (float)bi;
            __builtin_amdgcn_wave_barrier();
        }
    }
}

// ---------------------------------------------------------------- epilogue (R6-proven)
__global__ __launch_bounds__(256) void epilogue_kernel(
        const float* __restrict__ x, const float* __restrict__ cb,
        const float* __restrict__ zf, float* __restrict__ qout,
        double* __restrict__ partial) {
#pragma clang fp contract(off)
    const int gid = blockIdx.x * 256 + threadIdx.x;
    const int row = gid >> 2;
    const int d0  = (gid & 3) * 16;
    const float4* xr = reinterpret_cast<const float4*>(x + (size_t)row * DIM + d0);
    const int z = (int)zf[row];
    const float4* qr = reinterpret_cast<const float4*>(cb + (size_t)z * DIM + d0);
    float4* op = reinterpret_cast<float4*>(qout + (size_t)row * DIM + d0);

    double lsum = 0.0;
#pragma unroll
    for (int q = 0; q < 4; ++q) {
        float4 xv = xr[q];
        float4 qv = qr[q];
        float da = qv.x - xv.x, db = qv.y - xv.y, dc = qv.z - xv.z, dd = qv.w - xv.w;
        float4 o;
        o.x = xv.x + da; o.y = xv.y + db; o.z = xv.z + dc; o.w = xv.w + dd;
        op[q] = o;
        lsum += (double)(da * da) + (double)(db * db)
              + (double)(dc * dc) + (double)(dd * dd);
    }
#pragma unroll
    for (int s = 32; s >= 1; s >>= 1) lsum += __shfl_down(lsum, s, 64);
    __shared__ double wsum[4];
    const int lane = threadIdx.x & 63, wid = threadIdx.x >> 6;
    if (lane == 0) wsum[wid] = lsum;
    __syncthreads();
    if (threadIdx.x == 0)
        partial[blockIdx.x] = (wsum[0] + wsum[1]) + (wsum[2] + wsum[3]);
}

__global__ void finalize_kernel(const double* __restrict__ partial,
                                float* __restrict__ losses) {
    double s = 0.0;
    int lane = threadIdx.x;
    for (int i = lane; i < 4096; i += 64) s += partial[i];
#pragma unroll
    for (int sh = 32; sh >= 1; sh >>= 1) s += __shfl_down(s, sh, 64);
    if (lane == 0) {
        float v = (float)(s / 16777216.0);
        losses[0] = v;
        losses[1] = v;
    }
}

extern "C" void kernel_launch(void* const* d_in, const int* in_sizes, int n_in,
                              void* d_out, int out_size, void* d_ws, size_t ws_size,
                              hipStream_t stream) {
    const float* x  = (const float*)d_in[0];
    const float* cb = (const float*)d_in[1];
    float* out    = (float*)d_out;
    float* zout   = out;
    float* qout   = out + NROWS;
    float* losses = out + NROWS + (size_t)NROWS * DIM;

    float*          csq     = (float*)((char*)d_ws + CSQ_OFF);
    float*          cspre   = (float*)((char*)d_ws + CSPRE_OFF);
    unsigned short* csplit  = (unsigned short*)((char*)d_ws + CSPLIT_OFF);
    double*         partial = (double*)((char*)d_ws + PART_OFF);

    // cbT4 (256 KB) lives in the qout region of d_out: written by prep, read by
    // mega's phase 2, fully overwritten by the epilogue afterwards (R6-proven).
    float4* cbt4 = (float4*)qout;

    prep_kernel<<<16, 64, 0, stream>>>(cb, csq, cspre, csplit, cbt4);
    vq_mega_kernel<<<NROWS / 256, 256, 0, stream>>>(x, csplit, cspre, cbt4, csq, zout);
    epilogue_kernel<<<(NROWS * 4) / 256, 256, 0, stream>>>(x, cb, zout, qout, partial);
    finalize_kernel<<<1, 64, 0, stream>>>(partial, losses);
}

// Round 9
// 257.643 us; speedup vs baseline: 1.8011x; 1.2376x over previous
//
#include <hip/hip_runtime.h>
#include <math.h>
#include <limits.h>

// VQVAE: N=262144, K=1024, D=64. Outputs flat fp32: Z[N], q_with_st[N*64], 2 losses.
// R9 = R6 split pipeline (fusions regressed in R7/R8) + R8's validated u32-key
// scheme + 4 blocks/CU + f32 thread-partials in epilogue.
//  prep    : csq (exact), cspre = 65536*csq (exact), split codebook * -2^17, cbT4.
//  vq_mfma : bf16-split MFMA distances, swapped operands; key=(bits(acc+BIGC)<<10)+code,
//            u32 top-2; ambiguous rows appended to global list.
//  rescore : standalone 2048-block exact rescore (bitwise reference-matching fp32,
//            coalesced via cbT4) — verified absmax 0.0 rounds 1/3/4/5/6/8.
//  epilogue/finalize: gather + q_with_st + losses.

static constexpr int NROWS = 262144;
static constexpr int KC    = 1024;
static constexpr int DIM   = 64;
static constexpr int CAP   = 65536;

// d_ws layout (bytes); ws >= 565256 proven in rounds 4-6.
static constexpr size_t CSQ_OFF    = 0;          // 1024 f32
static constexpr size_t CSPRE_OFF  = 4096;       // 1024 f32 (= 65536*csq, exact)
static constexpr size_t CSPLIT_OFF = 8192;       // 256 KB -> ends 270336
static constexpr size_t CTR_OFF    = 270336;     // 1 int
static constexpr size_t LIST_OFF   = 270340;     // CAP ints -> ends 532484
static constexpr size_t PART_OFF   = 532488;     // 4096 doubles... (fits: 565256)

static constexpr float BIGC = 83886080.0f;       // 5 * 2^24

typedef __attribute__((ext_vector_type(8)))  short   short8;
typedef __attribute__((ext_vector_type(8)))  unsigned short ushort8;
typedef __attribute__((ext_vector_type(16))) float   f32x16;

static __device__ __forceinline__ unsigned short bf16rn(float f) {
    unsigned u = __float_as_uint(f);
    u += 0x7fffu + ((u >> 16) & 1u);      // round-nearest-even to bf16
    return (unsigned short)(u >> 16);
}
static __device__ __forceinline__ unsigned umin(unsigned a, unsigned b) { return a < b ? a : b; }
static __device__ __forceinline__ unsigned umax(unsigned a, unsigned b) { return a > b ? a : b; }

// ------------------------------------------------ prep
// csplit ushort index = chk*8192 + slot*512 + c_l*8 + e ; chk=c>>6, c_l=c&63
// slot for hi of dim d: d>>3 ; lo: 8+(d>>3) ; e = d&7. Values scaled by -2^17.
// cbT4[q*1024 + c] = cb[c][4q..4q+3] (fp32) -> lives in qout region until epilogue.
__global__ __launch_bounds__(64) void prep_kernel(const float* __restrict__ cb,
                                                  float* __restrict__ csq,
                                                  float* __restrict__ cspre,
                                                  unsigned short* __restrict__ cs,
                                                  float4* __restrict__ cbt4) {
#pragma clang fp contract(off)
    const int c = blockIdx.x * 64 + threadIdx.x;
    const float4* row = reinterpret_cast<const float4*>(cb + (size_t)c * DIM);
    float e[64];
#pragma unroll
    for (int q = 0; q < 16; ++q) {
        float4 v = row[q];
        cbt4[q * 1024 + c] = v;                         // transposed copy (coalesced)
        e[q * 4 + 0] = v.x; e[q * 4 + 1] = v.y;
        e[q * 4 + 2] = v.z; e[q * 4 + 3] = v.w;
    }
    float r[8];
#pragma unroll
    for (int g = 0; g < 8; ++g)
#pragma unroll
        for (int j = 0; j < 8; ++j) {
            float sq = e[8 * g + j] * e[8 * g + j];     // rounded square (no fma)
            if (g == 0) r[j] = sq; else r[j] += sq;
        }
    float s = ((r[0] + r[1]) + (r[2] + r[3])) + ((r[4] + r[5]) + (r[6] + r[7]));
    csq[c]   = s;
    cspre[c] = 65536.0f * s;                            // EXACT (pow2 scale)

    const int chk = c >> 6, c_l = c & 63;
    unsigned short* base = cs + (size_t)chk * 8192 + (size_t)c_l * 8;
#pragma unroll
    for (int g = 0; g < 8; ++g) {
        ushort8 hi, lo;
#pragma unroll
        for (int j = 0; j < 8; ++j) {
            float f = e[8 * g + j] * -131072.0f;        // exact pow2 scale
            unsigned short hb = bf16rn(f);
            float fh = __uint_as_float((unsigned)hb << 16);
            hi[j] = hb;
            lo[j] = bf16rn(f - fh);
        }
        *reinterpret_cast<ushort8*>(base + g * 512)       = hi;
        *reinterpret_cast<ushort8*>(base + (8 + g) * 512) = lo;
    }
}

// ------------------------------------------------ MFMA distance + packed-key argmin
#define STAGE(buf_, chk_) do {                                                          \
    const char* _s = (const char*)csplit + (size_t)(chk_) * 16384                       \
                     + (size_t)(w * 4) * 1024 + (size_t)lane * 16;                      \
    char* _d = (char*)(&bbuf[buf_][0]) + (size_t)(w * 4) * 1024;                        \
    _Pragma("unroll")                                                                   \
    for (int _it = 0; _it < 4; ++_it)                                                   \
        __builtin_amdgcn_global_load_lds(                                               \
            (const __attribute__((address_space(1))) unsigned int*)(_s + _it * 1024),   \
            (__attribute__((address_space(3))) unsigned int*)(_d + _it * 1024),         \
            16, 0, 0);                                                                  \
} while (0)

__global__ __launch_bounds__(256, 4) void vq_mfma_kernel(
        const float* __restrict__ x, const unsigned short* __restrict__ csplit,
        const float* __restrict__ cspre_g, float* __restrict__ zout,
        int* __restrict__ counter, int* __restrict__ list) {
    __shared__ unsigned short bbuf[2][8192];   // 32 KB
    __shared__ float cspre_s[1024];            // 4 KB

    const int tid  = threadIdx.x;
    const int w    = tid >> 6;
    const int lane = tid & 63;
    const int h    = lane >> 5;
    const int cl5  = lane & 31;
    const int rowbase = blockIdx.x * 256 + w * 64;

    STAGE(0, 0);
    {   // cspre -> LDS
        float4 v = reinterpret_cast<const float4*>(cspre_g)[tid];
        reinterpret_cast<float4*>(cspre_s)[tid] = v;
    }

    // x fragments (B-operand): bf16 hi/lo split in registers
    short8 xh[2][4], xl[2][4];
    float sa[2];
#pragma unroll
    for (int R = 0; R < 2; ++R) {
        const float* xrow = x + (size_t)(rowbase + R * 32 + cl5) * DIM;
        float s = 0.0f;
#pragma unroll
        for (int j = 0; j < 4; ++j) {
            float4 p0 = *reinterpret_cast<const float4*>(xrow + j * 16 + h * 8);
            float4 p1 = *reinterpret_cast<const float4*>(xrow + j * 16 + h * 8 + 4);
            float v[8] = {p0.x, p0.y, p0.z, p0.w, p1.x, p1.y, p1.z, p1.w};
#pragma unroll
            for (int e = 0; e < 8; ++e) {
                float f = v[e];
                s += fabsf(f);
                unsigned short hb = bf16rn(f);
                float fh = __uint_as_float((unsigned)hb << 16);
                xh[R][j][e] = (short)hb;
                xl[R][j][e] = (short)bf16rn(f - fh);
            }
        }
        s += __shfl_xor(s, 32, 64);            // complementary d-half, same row
        sa[R] = s;
    }
    __syncthreads();                           // chunk0 + cspre ready

    unsigned k1[2] = {0xFFFFFFFFu, 0xFFFFFFFFu};
    unsigned k2[2] = {0xFFFFFFFFu, 0xFFFFFFFFu};
    const int lofs = cl5 * 16 + h * 1024;
    static constexpr int IDX[16] = {0,1,2,3, 8,9,10,11, 16,17,18,19, 24,25,26,27};

    for (int chk = 0; chk < 16; ++chk) {
        const int cur = chk & 1;
        if (chk < 15) STAGE(cur ^ 1, chk + 1);
        const char* bb = (const char*)(&bbuf[cur][0]);
#pragma unroll
        for (int t = 0; t < 2; ++t) {
            const unsigned cbase = (unsigned)(chk * 64 + t * 32 + 4 * h);
            const float* cp = &cspre_s[chk * 64 + t * 32 + 4 * h];
            float4 g0 = *reinterpret_cast<const float4*>(cp);
            float4 g1 = *reinterpret_cast<const float4*>(cp + 8);
            float4 g2 = *reinterpret_cast<const float4*>(cp + 16);
            float4 g3 = *reinterpret_cast<const float4*>(cp + 24);
            f32x16 ini;
            ini[0]  = g0.x; ini[1]  = g0.y; ini[2]  = g0.z; ini[3]  = g0.w;
            ini[4]  = g1.x; ini[5]  = g1.y; ini[6]  = g1.z; ini[7]  = g1.w;
            ini[8]  = g2.x; ini[9]  = g2.y; ini[10] = g2.z; ini[11] = g2.w;
            ini[12] = g3.x; ini[13] = g3.y; ini[14] = g3.z; ini[15] = g3.w;

            const char* bp = bb + t * 512 + lofs;
            f32x16 a0, a1;
            {   // j = 0: ini is shared read-only C for both acc chains
                short8 bch = *reinterpret_cast<const short8*>(bp);
                short8 bcl = *reinterpret_cast<const short8*>(bp + 8192);
                a0 = __builtin_amdgcn_mfma_f32_32x32x16_bf16(bch, xh[0][0], ini, 0, 0, 0);
                a1 = __builtin_amdgcn_mfma_f32_32x32x16_bf16(bch, xh[1][0], ini, 0, 0, 0);
                a0 = __builtin_amdgcn_mfma_f32_32x32x16_bf16(bch, xl[0][0], a0, 0, 0, 0);
                a1 = __builtin_amdgcn_mfma_f32_32x32x16_bf16(bch, xl[1][0], a1, 0, 0, 0);
                a0 = __builtin_amdgcn_mfma_f32_32x32x16_bf16(bcl, xh[0][0], a0, 0, 0, 0);
                a1 = __builtin_amdgcn_mfma_f32_32x32x16_bf16(bcl, xh[1][0], a1, 0, 0, 0);
            }
#pragma unroll
            for (int j = 1; j < 4; ++j) {
                short8 bch = *reinterpret_cast<const short8*>(bp + j * 2048);
                short8 bcl = *reinterpret_cast<const short8*>(bp + 8192 + j * 2048);
                a0 = __builtin_amdgcn_mfma_f32_32x32x16_bf16(bch, xh[0][j], a0, 0, 0, 0);
                a1 = __builtin_amdgcn_mfma_f32_32x32x16_bf16(bch, xh[1][j], a1, 0, 0, 0);
                a0 = __builtin_amdgcn_mfma_f32_32x32x16_bf16(bch, xl[0][j], a0, 0, 0, 0);
                a1 = __builtin_amdgcn_mfma_f32_32x32x16_bf16(bch, xl[1][j], a1, 0, 0, 0);
                a0 = __builtin_amdgcn_mfma_f32_32x32x16_bf16(bcl, xh[0][j], a0, 0, 0, 0);
                a1 = __builtin_amdgcn_mfma_f32_32x32x16_bf16(bcl, xh[1][j], a1, 0, 0, 0);
            }
            // acc = 65536*(csq - 2*dot); z = acc + BIGC (<=0.5 ulp);
            // key = (bits(z)<<10)+code : u32-monotone (const exponent, bit22=0).
#pragma unroll
            for (int p = 0; p < 8; ++p) {
                const int r = 2 * p, r2 = 2 * p + 1;
                {
                    unsigned ka = (__float_as_uint(a0[r]  + BIGC) << 10) + cbase + IDX[r];
                    unsigned kb = (__float_as_uint(a0[r2] + BIGC) << 10) + cbase + IDX[r2];
                    unsigned pmin = umin(ka, kb), pmax = umax(ka, kb);
                    unsigned tt = umax(pmin, k1[0]);
                    k2[0] = umin(umin(k2[0], tt), pmax);   // v_min3
                    k1[0] = umin(k1[0], pmin);
                }
                {
                    unsigned ka = (__float_as_uint(a1[r]  + BIGC) << 10) + cbase + IDX[r];
                    unsigned kb = (__float_as_uint(a1[r2] + BIGC) << 10) + cbase + IDX[r2];
                    unsigned pmin = umin(ka, kb), pmax = umax(ka, kb);
                    unsigned tt = umax(pmin, k1[1]);
                    k2[1] = umin(umin(k2[1], tt), pmax);
                    k1[1] = umin(k1[1], pmin);
                }
            }
        }
        __syncthreads();           // my reads done; staged chunk landed
    }

    // merge complementary code-subsets (lane <-> lane^32)
    unsigned K1[2], K2[2];
#pragma unroll
    for (int R = 0; R < 2; ++R) {
        unsigned o1 = (unsigned)__shfl_xor((int)k1[R], 32, 64);
        unsigned o2 = (unsigned)__shfl_xor((int)k2[R], 32, 64);
        unsigned mn = umin(k1[R], o1), mx = umax(k1[R], o1);
        K1[R] = mn;
        K2[R] = umin(umin(k2[R], o2), mx);
    }
    {
        const unsigned bk1 = h ? K1[1] : K1[0];
        const unsigned bk2 = h ? K2[1] : K2[0];
        const float    SA  = h ? sa[1] : sa[0];
        const int row = rowbase + h * 32 + cl5;
        zout[row] = (float)(bk1 & 1023u);
        // key-bit quantum = 1.22e-4 dist (8192 = 1/1.22e-4)  [R8-validated]
        unsigned Tq = (unsigned)(8192.0f * (1.2e-4f * SA + 8e-4f)) + 2u;
        if ((bk2 - bk1) < (Tq << 10)) {
            int id = atomicAdd(counter, 1);
            if (id < CAP) list[id] = row;
        }
    }
}

// ---------------------------------------------------------------- exact rescore (bitwise ref)
__global__ __launch_bounds__(256) void rescore_kernel(
        const float* __restrict__ x, const float4* __restrict__ cbt4,
        const float* __restrict__ csq, const int* __restrict__ counter,
        const int* __restrict__ list, float* __restrict__ zout) {
#pragma clang fp contract(off)
    __shared__ float xs[4][64];
    const int w    = threadIdx.x >> 6;
    const int lane = threadIdx.x & 63;
    const int wglobal = blockIdx.x * 4 + w;
    const int wstride = gridDim.x * 4;
    int cnt = *counter; if (cnt > CAP) cnt = CAP;

    for (int i = wglobal; i < cnt; i += wstride) {
        const int row = list[i];
        if (lane < 16) {
            float4 v = reinterpret_cast<const float4*>(x + (size_t)row * DIM)[lane];
            *reinterpret_cast<float4*>(&xs[w][lane * 4]) = v;
        }
        __builtin_amdgcn_wave_barrier();

        float r8[8];
#pragma unroll
        for (int g = 0; g < 8; ++g)
#pragma unroll
            for (int j = 0; j < 8; ++j) {
                float xv = xs[w][8 * g + j];
                float sq = xv * xv;
                if (g == 0) r8[j] = sq; else r8[j] += sq;
            }
        float xsq = ((r8[0] + r8[1]) + (r8[2] + r8[3])) + ((r8[4] + r8[5]) + (r8[6] + r8[7]));

        float bm = INFINITY; int bi = 0;
#pragma unroll 2
        for (int cc = 0; cc < 16; ++cc) {
            int c = cc * 64 + lane;                   // in-lane ascending
            float dot = 0.0f;
#pragma unroll
            for (int q = 0; q < 16; ++q) {
                float4 v  = cbt4[q * 1024 + c];       // coalesced
                float4 xv = *reinterpret_cast<const float4*>(&xs[w][q * 4]);
                dot = __builtin_fmaf(v.x, xv.x, dot);
                dot = __builtin_fmaf(v.y, xv.y, dot);
                dot = __builtin_fmaf(v.z, xv.z, dot);
                dot = __builtin_fmaf(v.w, xv.w, dot);
            }
            float dist = (xsq - 2.0f * dot) + csq[c];
            if (dist < bm) { bm = dist; bi = c; }
        }
#pragma unroll
        for (int m = 1; m <= 32; m <<= 1) {
            float ov = __shfl_xor(bm, m, 64);
            int   oi = __shfl_xor(bi, m, 64);
            if (ov < bm || (ov == bm && oi < bi)) { bm = ov; bi = oi; }
        }
        if (lane == 0) zout[row] = (float)bi;
        __builtin_amdgcn_wave_barrier();
    }
}

// ---------------------------------------------------------------- epilogue
// f32 per-thread partial (16 adds), f64 from wave-reduce on (DP rate is the
// R6 epilogue's suspected long pole).
__global__ __launch_bounds__(256) void epilogue_kernel(
        const float* __restrict__ x, const float* __restrict__ cb,
        const float* __restrict__ zf, float* __restrict__ qout,
        double* __restrict__ partial) {
#pragma clang fp contract(off)
    const int gid = blockIdx.x * 256 + threadIdx.x;
    const int row = gid >> 2;
    const int d0  = (gid & 3) * 16;
    const float4* xr = reinterpret_cast<const float4*>(x + (size_t)row * DIM + d0);
    const int z = (int)zf[row];
    const float4* qr = reinterpret_cast<const float4*>(cb + (size_t)z * DIM + d0);
    float4* op = reinterpret_cast<float4*>(qout + (size_t)row * DIM + d0);

    float lf = 0.0f;
#pragma unroll
    for (int q = 0; q < 4; ++q) {
        float4 xv = xr[q];
        float4 qv = qr[q];
        float da = qv.x - xv.x, db = qv.y - xv.y, dc = qv.z - xv.z, dd = qv.w - xv.w;
        float4 o;
        o.x = xv.x + da; o.y = xv.y + db; o.z = xv.z + dc; o.w = xv.w + dd;
        op[q] = o;
        lf += da * da; lf += db * db; lf += dc * dc; lf += dd * dd;
    }
    double lsum = (double)lf;
#pragma unroll
    for (int s = 32; s >= 1; s >>= 1) lsum += __shfl_down(lsum, s, 64);
    __shared__ double wsum[4];
    const int lane = threadIdx.x & 63, wid = threadIdx.x >> 6;
    if (lane == 0) wsum[wid] = lsum;
    __syncthreads();
    if (threadIdx.x == 0)
        partial[blockIdx.x] = (wsum[0] + wsum[1]) + (wsum[2] + wsum[3]);
}

__global__ void finalize_kernel(const double* __restrict__ partial,
                                float* __restrict__ losses) {
    double s = 0.0;
    int lane = threadIdx.x;
    for (int i = lane; i < 4096; i += 64) s += partial[i];
#pragma unroll
    for (int sh = 32; sh >= 1; sh >>= 1) s += __shfl_down(s, sh, 64);
    if (lane == 0) {
        float v = (float)(s / 16777216.0);
        losses[0] = v;
        losses[1] = v;
    }
}

extern "C" void kernel_launch(void* const* d_in, const int* in_sizes, int n_in,
                              void* d_out, int out_size, void* d_ws, size_t ws_size,
                              hipStream_t stream) {
    const float* x  = (const float*)d_in[0];
    const float* cb = (const float*)d_in[1];
    float* out    = (float*)d_out;
    float* zout   = out;
    float* qout   = out + NROWS;
    float* losses = out + NROWS + (size_t)NROWS * DIM;

    float*          csq     = (float*)((char*)d_ws + CSQ_OFF);
    float*          cspre   = (float*)((char*)d_ws + CSPRE_OFF);
    unsigned short* csplit  = (unsigned short*)((char*)d_ws + CSPLIT_OFF);
    int*            counter = (int*)((char*)d_ws + CTR_OFF);
    int*            list    = (int*)((char*)d_ws + LIST_OFF);
    double*         partial = (double*)((char*)d_ws + PART_OFF);

    // cbT4 (256 KB) lives in the qout region of d_out: written by prep, read by
    // rescore, fully overwritten by the epilogue afterwards (R6-proven).
    float4* cbt4 = (float4*)qout;

    hipMemsetAsync(counter, 0, sizeof(int), stream);
    prep_kernel<<<16, 64, 0, stream>>>(cb, csq, cspre, csplit, cbt4);
    vq_mfma_kernel<<<NROWS / 256, 256, 0, stream>>>(x, csplit, cspre, zout, counter, list);
    rescore_kernel<<<2048, 256, 0, stream>>>(x, cbt4, csq, counter, list, zout);
    epilogue_kernel<<<(NROWS * 4) / 256, 256, 0, stream>>>(x, cb, zout, qout, partial);
    finalize_kernel<<<1, 64, 0, stream>>>(partial, losses);
}

// Round 10
// 252.957 us; speedup vs baseline: 1.8344x; 1.0185x over previous
//
#include <hip/hip_runtime.h>
#include <math.h>
#include <limits.h>

// VQVAE: N=262144, K=1024, D=64. Outputs flat fp32: Z[N], q_with_st[N*64], 2 losses.
// R10: vq back to launch_bounds(256,3) (R9's (256,4) caused 60MB scratch spill);
// rescore redesigned to ONE ROW PER BLOCK (256 threads, 4 codes/thread) — R6/R9's
// 1-wave-per-row rescore ran at serialized-load latency (~95us wall for ~5k rows).
// Key scheme (R8/R9-validated, absmax 0): acc init = 65536*csq (exact), codebook
// scaled by -2^17, key = (bits(acc+BIGC)<<10)+code u32-monotone; ambiguous rows
// (top-2 gap <= Tq) rescored with the bitwise reference-matching fp32 formula.

static constexpr int NROWS = 262144;
static constexpr int KC    = 1024;
static constexpr int DIM   = 64;
static constexpr int CAP   = 65536;

// d_ws layout (bytes); ws >= 565256 proven in rounds 4-6.
static constexpr size_t CSQ_OFF    = 0;          // 1024 f32
static constexpr size_t CSPRE_OFF  = 4096;       // 1024 f32 (= 65536*csq, exact)
static constexpr size_t CSPLIT_OFF = 8192;       // 256 KB -> ends 270336
static constexpr size_t CTR_OFF    = 270336;     // 1 int
static constexpr size_t LIST_OFF   = 270340;     // CAP ints -> ends 532484
static constexpr size_t PART_OFF   = 532488;     // 4096 doubles (fits: 565256)

static constexpr float BIGC = 83886080.0f;       // 5 * 2^24

typedef __attribute__((ext_vector_type(8)))  short   short8;
typedef __attribute__((ext_vector_type(8)))  unsigned short ushort8;
typedef __attribute__((ext_vector_type(16))) float   f32x16;

static __device__ __forceinline__ unsigned short bf16rn(float f) {
    unsigned u = __float_as_uint(f);
    u += 0x7fffu + ((u >> 16) & 1u);      // round-nearest-even to bf16
    return (unsigned short)(u >> 16);
}
static __device__ __forceinline__ unsigned umin(unsigned a, unsigned b) { return a < b ? a : b; }
static __device__ __forceinline__ unsigned umax(unsigned a, unsigned b) { return a > b ? a : b; }

// ------------------------------------------------ prep
// csplit ushort index = chk*8192 + slot*512 + c_l*8 + e ; chk=c>>6, c_l=c&63
// slot for hi of dim d: d>>3 ; lo: 8+(d>>3) ; e = d&7. Values scaled by -2^17.
// cbT4[q*1024 + c] = cb[c][4q..4q+3] (fp32) -> lives in qout region until epilogue.
// Also zeroes the rescore counter (prep precedes vq on the stream).
__global__ __launch_bounds__(64) void prep_kernel(const float* __restrict__ cb,
                                                  float* __restrict__ csq,
                                                  float* __restrict__ cspre,
                                                  unsigned short* __restrict__ cs,
                                                  float4* __restrict__ cbt4,
                                                  int* __restrict__ counter) {
#pragma clang fp contract(off)
    if (blockIdx.x == 0 && threadIdx.x == 0) *counter = 0;
    const int c = blockIdx.x * 64 + threadIdx.x;
    const float4* row = reinterpret_cast<const float4*>(cb + (size_t)c * DIM);
    float e[64];
#pragma unroll
    for (int q = 0; q < 16; ++q) {
        float4 v = row[q];
        cbt4[q * 1024 + c] = v;                         // transposed copy (coalesced)
        e[q * 4 + 0] = v.x; e[q * 4 + 1] = v.y;
        e[q * 4 + 2] = v.z; e[q * 4 + 3] = v.w;
    }
    float r[8];
#pragma unroll
    for (int g = 0; g < 8; ++g)
#pragma unroll
        for (int j = 0; j < 8; ++j) {
            float sq = e[8 * g + j] * e[8 * g + j];     // rounded square (no fma)
            if (g == 0) r[j] = sq; else r[j] += sq;
        }
    float s = ((r[0] + r[1]) + (r[2] + r[3])) + ((r[4] + r[5]) + (r[6] + r[7]));
    csq[c]   = s;
    cspre[c] = 65536.0f * s;                            // EXACT (pow2 scale)

    const int chk = c >> 6, c_l = c & 63;
    unsigned short* base = cs + (size_t)chk * 8192 + (size_t)c_l * 8;
#pragma unroll
    for (int g = 0; g < 8; ++g) {
        ushort8 hi, lo;
#pragma unroll
        for (int j = 0; j < 8; ++j) {
            float f = e[8 * g + j] * -131072.0f;        // exact pow2 scale
            unsigned short hb = bf16rn(f);
            float fh = __uint_as_float((unsigned)hb << 16);
            hi[j] = hb;
            lo[j] = bf16rn(f - fh);
        }
        *reinterpret_cast<ushort8*>(base + g * 512)       = hi;
        *reinterpret_cast<ushort8*>(base + (8 + g) * 512) = lo;
    }
}

// ------------------------------------------------ MFMA distance + packed-key argmin
#define STAGE(buf_, chk_) do {                                                          \
    const char* _s = (const char*)csplit + (size_t)(chk_) * 16384                       \
                     + (size_t)(w * 4) * 1024 + (size_t)lane * 16;                      \
    char* _d = (char*)(&bbuf[buf_][0]) + (size_t)(w * 4) * 1024;                        \
    _Pragma("unroll")                                                                   \
    for (int _it = 0; _it < 4; ++_it)                                                   \
        __builtin_amdgcn_global_load_lds(                                               \
            (const __attribute__((address_space(1))) unsigned int*)(_s + _it * 1024),   \
            (__attribute__((address_space(3))) unsigned int*)(_d + _it * 1024),         \
            16, 0, 0);                                                                  \
} while (0)

__global__ __launch_bounds__(256, 3) void vq_mfma_kernel(
        const float* __restrict__ x, const unsigned short* __restrict__ csplit,
        const float* __restrict__ cspre_g, float* __restrict__ zout,
        int* __restrict__ counter, int* __restrict__ list) {
    __shared__ unsigned short bbuf[2][8192];   // 32 KB
    __shared__ float cspre_s[1024];            // 4 KB

    const int tid  = threadIdx.x;
    const int w    = tid >> 6;
    const int lane = tid & 63;
    const int h    = lane >> 5;
    const int cl5  = lane & 31;
    const int rowbase = blockIdx.x * 256 + w * 64;

    STAGE(0, 0);
    {   // cspre -> LDS
        float4 v = reinterpret_cast<const float4*>(cspre_g)[tid];
        reinterpret_cast<float4*>(cspre_s)[tid] = v;
    }

    // x fragments (B-operand): bf16 hi/lo split in registers
    short8 xh[2][4], xl[2][4];
    float sa[2];
#pragma unroll
    for (int R = 0; R < 2; ++R) {
        const float* xrow = x + (size_t)(rowbase + R * 32 + cl5) * DIM;
        float s = 0.0f;
#pragma unroll
        for (int j = 0; j < 4; ++j) {
            float4 p0 = *reinterpret_cast<const float4*>(xrow + j * 16 + h * 8);
            float4 p1 = *reinterpret_cast<const float4*>(xrow + j * 16 + h * 8 + 4);
            float v[8] = {p0.x, p0.y, p0.z, p0.w, p1.x, p1.y, p1.z, p1.w};
#pragma unroll
            for (int e = 0; e < 8; ++e) {
                float f = v[e];
                s += fabsf(f);
                unsigned short hb = bf16rn(f);
                float fh = __uint_as_float((unsigned)hb << 16);
                xh[R][j][e] = (short)hb;
                xl[R][j][e] = (short)bf16rn(f - fh);
            }
        }
        s += __shfl_xor(s, 32, 64);            // complementary d-half, same row
        sa[R] = s;
    }
    __syncthreads();                           // chunk0 + cspre ready

    unsigned k1[2] = {0xFFFFFFFFu, 0xFFFFFFFFu};
    unsigned k2[2] = {0xFFFFFFFFu, 0xFFFFFFFFu};
    const int lofs = cl5 * 16 + h * 1024;
    static constexpr int IDX[16] = {0,1,2,3, 8,9,10,11, 16,17,18,19, 24,25,26,27};

    for (int chk = 0; chk < 16; ++chk) {
        const int cur = chk & 1;
        if (chk < 15) STAGE(cur ^ 1, chk + 1);
        const char* bb = (const char*)(&bbuf[cur][0]);
#pragma unroll
        for (int t = 0; t < 2; ++t) {
            const unsigned cbase = (unsigned)(chk * 64 + t * 32 + 4 * h);
            const float* cp = &cspre_s[chk * 64 + t * 32 + 4 * h];
            float4 g0 = *reinterpret_cast<const float4*>(cp);
            float4 g1 = *reinterpret_cast<const float4*>(cp + 8);
            float4 g2 = *reinterpret_cast<const float4*>(cp + 16);
            float4 g3 = *reinterpret_cast<const float4*>(cp + 24);
            f32x16 ini;
            ini[0]  = g0.x; ini[1]  = g0.y; ini[2]  = g0.z; ini[3]  = g0.w;
            ini[4]  = g1.x; ini[5]  = g1.y; ini[6]  = g1.z; ini[7]  = g1.w;
            ini[8]  = g2.x; ini[9]  = g2.y; ini[10] = g2.z; ini[11] = g2.w;
            ini[12] = g3.x; ini[13] = g3.y; ini[14] = g3.z; ini[15] = g3.w;

            const char* bp = bb + t * 512 + lofs;
            f32x16 a0, a1;
            {   // j = 0: ini is shared read-only C for both acc chains
                short8 bch = *reinterpret_cast<const short8*>(bp);
                short8 bcl = *reinterpret_cast<const short8*>(bp + 8192);
                a0 = __builtin_amdgcn_mfma_f32_32x32x16_bf16(bch, xh[0][0], ini, 0, 0, 0);
                a1 = __builtin_amdgcn_mfma_f32_32x32x16_bf16(bch, xh[1][0], ini, 0, 0, 0);
                a0 = __builtin_amdgcn_mfma_f32_32x32x16_bf16(bch, xl[0][0], a0, 0, 0, 0);
                a1 = __builtin_amdgcn_mfma_f32_32x32x16_bf16(bch, xl[1][0], a1, 0, 0, 0);
                a0 = __builtin_amdgcn_mfma_f32_32x32x16_bf16(bcl, xh[0][0], a0, 0, 0, 0);
                a1 = __builtin_amdgcn_mfma_f32_32x32x16_bf16(bcl, xh[1][0], a1, 0, 0, 0);
            }
#pragma unroll
            for (int j = 1; j < 4; ++j) {
                short8 bch = *reinterpret_cast<const short8*>(bp + j * 2048);
                short8 bcl = *reinterpret_cast<const short8*>(bp + 8192 + j * 2048);
                a0 = __builtin_amdgcn_mfma_f32_32x32x16_bf16(bch, xh[0][j], a0, 0, 0, 0);
                a1 = __builtin_amdgcn_mfma_f32_32x32x16_bf16(bch, xh[1][j], a1, 0, 0, 0);
                a0 = __builtin_amdgcn_mfma_f32_32x32x16_bf16(bch, xl[0][j], a0, 0, 0, 0);
                a1 = __builtin_amdgcn_mfma_f32_32x32x16_bf16(bch, xl[1][j], a1, 0, 0, 0);
                a0 = __builtin_amdgcn_mfma_f32_32x32x16_bf16(bcl, xh[0][j], a0, 0, 0, 0);
                a1 = __builtin_amdgcn_mfma_f32_32x32x16_bf16(bcl, xh[1][j], a1, 0, 0, 0);
            }
            // acc = 65536*(csq - 2*dot); z = acc + BIGC (<=0.5 ulp);
            // key = (bits(z)<<10)+code : u32-monotone (const exponent, bit22=0).
#pragma unroll
            for (int p = 0; p < 8; ++p) {
                const int r = 2 * p, r2 = 2 * p + 1;
                {
                    unsigned ka = (__float_as_uint(a0[r]  + BIGC) << 10) + cbase + IDX[r];
                    unsigned kb = (__float_as_uint(a0[r2] + BIGC) << 10) + cbase + IDX[r2];
                    unsigned pmin = umin(ka, kb), pmax = umax(ka, kb);
                    unsigned tt = umax(pmin, k1[0]);
                    k2[0] = umin(umin(k2[0], tt), pmax);   // v_min3
                    k1[0] = umin(k1[0], pmin);
                }
                {
                    unsigned ka = (__float_as_uint(a1[r]  + BIGC) << 10) + cbase + IDX[r];
                    unsigned kb = (__float_as_uint(a1[r2] + BIGC) << 10) + cbase + IDX[r2];
                    unsigned pmin = umin(ka, kb), pmax = umax(ka, kb);
                    unsigned tt = umax(pmin, k1[1]);
                    k2[1] = umin(umin(k2[1], tt), pmax);
                    k1[1] = umin(k1[1], pmin);
                }
            }
        }
        __syncthreads();           // my reads done; staged chunk landed
    }

    // merge complementary code-subsets (lane <-> lane^32)
    unsigned K1[2], K2[2];
#pragma unroll
    for (int R = 0; R < 2; ++R) {
        unsigned o1 = (unsigned)__shfl_xor((int)k1[R], 32, 64);
        unsigned o2 = (unsigned)__shfl_xor((int)k2[R], 32, 64);
        unsigned mn = umin(k1[R], o1), mx = umax(k1[R], o1);
        K1[R] = mn;
        K2[R] = umin(umin(k2[R], o2), mx);
    }
    {
        const unsigned bk1 = h ? K1[1] : K1[0];
        const unsigned bk2 = h ? K2[1] : K2[0];
        const float    SA  = h ? sa[1] : sa[0];
        const int row = rowbase + h * 32 + cl5;
        zout[row] = (float)(bk1 & 1023u);
        // key-bit quantum = 1.22e-4 dist (8192 = 1/1.22e-4)  [R8/R9-validated]
        unsigned Tq = (unsigned)(8192.0f * (1.2e-4f * SA + 8e-4f)) + 2u;
        if ((bk2 - bk1) < (Tq << 10)) {
            int id = atomicAdd(counter, 1);
            if (id < CAP) list[id] = row;
        }
    }
}

// ---------------------------------------------------------------- exact rescore (bitwise ref)
// R10: one ROW per BLOCK; thread owns codes c = cc*256 + tid (4 independent dot
// chains). Math/order bitwise-identical to verified body (rounds 1/3/4/5/6/8/9).
__global__ __launch_bounds__(256) void rescore_kernel(
        const float* __restrict__ x, const float4* __restrict__ cbt4,
        const float* __restrict__ csq, const int* __restrict__ counter,
        const int* __restrict__ list, float* __restrict__ zout) {
#pragma clang fp contract(off)
    __shared__ float xs[64];
    __shared__ float bval[4];
    __shared__ int   bidx[4];
    const int tid  = threadIdx.x;
    const int lane = tid & 63;
    const int w    = tid >> 6;
    int cnt = *counter; if (cnt > CAP) cnt = CAP;

    for (int i = blockIdx.x; i < cnt; i += gridDim.x) {
        const int row = list[i];
        if (tid < 16) {
            float4 v = reinterpret_cast<const float4*>(x + (size_t)row * DIM)[tid];
            *reinterpret_cast<float4*>(&xs[tid * 4]) = v;
        }
        __syncthreads();

        // x_sq: numpy pairwise structure from LDS (broadcast)
        float r8[8];
#pragma unroll
        for (int g = 0; g < 8; ++g)
#pragma unroll
            for (int j = 0; j < 8; ++j) {
                float xv = xs[8 * g + j];
                float sq = xv * xv;
                if (g == 0) r8[j] = sq; else r8[j] += sq;
            }
        float xsq = ((r8[0] + r8[1]) + (r8[2] + r8[3])) + ((r8[4] + r8[5]) + (r8[6] + r8[7]));

        float bm = INFINITY; int bi = 0;
#pragma unroll
        for (int cc = 0; cc < 4; ++cc) {
            const int c = cc * 256 + tid;             // in-thread ascending
            float dot = 0.0f;
#pragma unroll
            for (int q = 0; q < 16; ++q) {
                float4 v  = cbt4[q * 1024 + c];       // coalesced across block
                float4 xv = *reinterpret_cast<const float4*>(&xs[q * 4]);
                dot = __builtin_fmaf(v.x, xv.x, dot);
                dot = __builtin_fmaf(v.y, xv.y, dot);
                dot = __builtin_fmaf(v.z, xv.z, dot);
                dot = __builtin_fmaf(v.w, xv.w, dot);
            }
            float dist = (xsq - 2.0f * dot) + csq[c];
            if (dist < bm) { bm = dist; bi = c; }
        }
        // wave-level lex (val, idx) min, then cross-wave via LDS
#pragma unroll
        for (int m = 1; m <= 32; m <<= 1) {
            float ov = __shfl_xor(bm, m, 64);
            int   oi = __shfl_xor(bi, m, 64);
            if (ov < bm || (ov == bm && oi < bi)) { bm = ov; bi = oi; }
        }
        if (lane == 0) { bval[w] = bm; bidx[w] = bi; }
        __syncthreads();
        if (tid == 0) {
            float v = bval[0]; int ix = bidx[0];
#pragma unroll
            for (int k = 1; k < 4; ++k)
                if (bval[k] < v || (bval[k] == v && bidx[k] < ix)) { v = bval[k]; ix = bidx[k]; }
            zout[row] = (float)ix;
        }
        __syncthreads();    // xs/bval reused next iteration
    }
}

// ---------------------------------------------------------------- epilogue
__global__ __launch_bounds__(256) void epilogue_kernel(
        const float* __restrict__ x, const float* __restrict__ cb,
        const float* __restrict__ zf, float* __restrict__ qout,
        double* __restrict__ partial) {
#pragma clang fp contract(off)
    const int gid = blockIdx.x * 256 + threadIdx.x;
    const int row = gid >> 2;
    const int d0  = (gid & 3) * 16;
    const float4* xr = reinterpret_cast<const float4*>(x + (size_t)row * DIM + d0);
    const int z = (int)zf[row];
    const float4* qr = reinterpret_cast<const float4*>(cb + (size_t)z * DIM + d0);
    float4* op = reinterpret_cast<float4*>(qout + (size_t)row * DIM + d0);

    float lf = 0.0f;
#pragma unroll
    for (int q = 0; q < 4; ++q) {
        float4 xv = xr[q];
        float4 qv = qr[q];
        float da = qv.x - xv.x, db = qv.y - xv.y, dc = qv.z - xv.z, dd = qv.w - xv.w;
        float4 o;
        o.x = xv.x + da; o.y = xv.y + db; o.z = xv.z + dc; o.w = xv.w + dd;
        op[q] = o;
        lf += da * da; lf += db * db; lf += dc * dc; lf += dd * dd;
    }
    double lsum = (double)lf;
#pragma unroll
    for (int s = 32; s >= 1; s >>= 1) lsum += __shfl_down(lsum, s, 64);
    __shared__ double wsum[4];
    const int lane = threadIdx.x & 63, wid = threadIdx.x >> 6;
    if (lane == 0) wsum[wid] = lsum;
    __syncthreads();
    if (threadIdx.x == 0)
        partial[blockIdx.x] = (wsum[0] + wsum[1]) + (wsum[2] + wsum[3]);
}

__global__ void finalize_kernel(const double* __restrict__ partial,
                                float* __restrict__ losses) {
    double s = 0.0;
    int lane = threadIdx.x;
    for (int i = lane; i < 4096; i += 64) s += partial[i];
#pragma unroll
    for (int sh = 32; sh >= 1; sh >>= 1) s += __shfl_down(s, sh, 64);
    if (lane == 0) {
        float v = (float)(s / 16777216.0);
        losses[0] = v;
        losses[1] = v;
    }
}

extern "C" void kernel_launch(void* const* d_in, const int* in_sizes, int n_in,
                              void* d_out, int out_size, void* d_ws, size_t ws_size,
                              hipStream_t stream) {
    const float* x  = (const float*)d_in[0];
    const float* cb = (const float*)d_in[1];
    float* out    = (float*)d_out;
    float* zout   = out;
    float* qout   = out + NROWS;
    float* losses = out + NROWS + (size_t)NROWS * DIM;

    float*          csq     = (float*)((char*)d_ws + CSQ_OFF);
    float*          cspre   = (float*)((char*)d_ws + CSPRE_OFF);
    unsigned short* csplit  = (unsigned short*)((char*)d_ws + CSPLIT_OFF);
    int*            counter = (int*)((char*)d_ws + CTR_OFF);
    int*            list    = (int*)((char*)d_ws + LIST_OFF);
    double*         partial = (double*)((char*)d_ws + PART_OFF);

    // cbT4 (256 KB) lives in the qout region of d_out: written by prep, read by
    // rescore, fully overwritten by the epilogue afterwards (R6-proven).
    float4* cbt4 = (float4*)qout;

    prep_kernel<<<16, 64, 0, stream>>>(cb, csq, cspre, csplit, cbt4, counter);
    vq_mfma_kernel<<<NROWS / 256, 256, 0, stream>>>(x, csplit, cspre, zout, counter, list);
    rescore_kernel<<<4096, 256, 0, stream>>>(x, cbt4, csq, counter, list, zout);
    epilogue_kernel<<<(NROWS * 4) / 256, 256, 0, stream>>>(x, cb, zout, qout, partial);
    finalize_kernel<<<1, 64, 0, stream>>>(partial, losses);
}